// Round 6
// baseline (93.076 us; speedup 1.0000x reference)
//
#include <hip/hip_runtime.h>
#include <stdint.h>

#define DIM 256
#define BATCH 16384
#define MARGIN 1.0f
#define EPSV 1e-6f

#define PPB 8                    // pairs per block (4 waves, 2 pairs/wave)
#define NBLOCKS (BATCH / PPB)    // 2048 blocks
#define FXSCALE 4294967296.0     // 2^32 fixed-point scale for deterministic atomic sum

typedef float fx4 __attribute__((ext_vector_type(4)));

__device__ __forceinline__ float dot4(fx4 a, fx4 b) {
    return a.x * b.x + a.y * b.y + a.z * b.z + a.w * b.w;
}

// Async global->LDS, 16B per lane. LDS dest is wave-uniform base + lane*16 (HW rule);
// global src is per-lane. One call moves one full 1KB row per wave.
__device__ __forceinline__ void gload_lds16(const void* g, void* l) {
    __builtin_amdgcn_global_load_lds(
        (const __attribute__((address_space(1))) uint32_t*)g,
        (__attribute__((address_space(3))) uint32_t*)l, 16, 0, 0);
}

// Block stages 8 pairs x 8 entity rows = 64 KB LDS via DMA, computes 8 relu terms,
// then adds its partial into a fixed-point u64 accumulator; last block writes out.
__global__ __launch_bounds__(256, 2) void transd_loss_kernel(
    const int* __restrict__ pos_x, const int* __restrict__ neg_x,
    const float* __restrict__ ent, const float* __restrict__ entm,
    const float* __restrict__ rel, const float* __restrict__ relm,
    unsigned long long* __restrict__ acc, unsigned int* __restrict__ done,
    float* __restrict__ out) {
    __shared__ float rows[64 * DIM];  // 64 KB
    __shared__ float wsum[4];

    const int tid  = threadIdx.x;
    const int w    = tid >> 6;
    const int lane = tid & 63;
    const int g0   = blockIdx.x * PPB;

    // --- wave-uniform indices for this wave's 2 pairs x 2 sides ---
    int hidx[2][2], ridx[2][2], tidx[2][2];
#pragma unroll
    for (int p2 = 0; p2 < 2; ++p2) {
        const int p = 2 * w + p2;
#pragma unroll
        for (int s = 0; s < 2; ++s) {
            const int* __restrict__ tri = s ? neg_x : pos_x;
            hidx[p2][s] = tri[(g0 + p) * 3 + 0];
            ridx[p2][s] = tri[(g0 + p) * 3 + 1];
            tidx[p2][s] = tri[(g0 + p) * 3 + 2];
        }
    }

    // --- issue 16 row-DMAs (4 rows per pair-side), zero data VGPRs ---
    const int lf = lane * 4;  // float offset = 16B/lane
#pragma unroll
    for (int p2 = 0; p2 < 2; ++p2) {
        const int p = 2 * w + p2;
#pragma unroll
        for (int s = 0; s < 2; ++s) {
            float* rb = &rows[(p * 8 + s * 4) * DIM];
            const size_t ho = (size_t)hidx[p2][s] * DIM + lf;
            const size_t to = (size_t)tidx[p2][s] * DIM + lf;
            gload_lds16(ent  + ho, rb + 0 * DIM);
            gload_lds16(entm + ho, rb + 1 * DIM);
            gload_lds16(ent  + to, rb + 2 * DIM);
            gload_lds16(entm + to, rb + 3 * DIM);
        }
    }

    // --- relation rows to regs (1MB tables, L2/L3-hot) ---
    fx4 rv[2][2], rpv[2][2];
#pragma unroll
    for (int p2 = 0; p2 < 2; ++p2) {
#pragma unroll
        for (int s = 0; s < 2; ++s) {
            const size_t ro = (size_t)ridx[p2][s] * DIM + lf;
            rv[p2][s]  = *(const fx4*)(rel  + ro);
            rpv[p2][s] = *(const fx4*)(relm + ro);
        }
    }

    __syncthreads();  // drains vmcnt (DMA + rel loads), then barrier

    // --- compute: 2 pairs, pos/neg interleaved shuffle chains ---
    float accf = 0.0f;
#pragma unroll
    for (int p2 = 0; p2 < 2; ++p2) {
        const int p  = 2 * w + p2;
        const float* rb0 = &rows[(p * 8 + 0) * DIM];  // pos: h,hp,t,tp
        const float* rb1 = &rows[(p * 8 + 4) * DIM];  // neg: h,hp,t,tp
        fx4 h0  = *(const fx4*)(rb0 + 0 * DIM + lf);
        fx4 hp0 = *(const fx4*)(rb0 + 1 * DIM + lf);
        fx4 t0  = *(const fx4*)(rb0 + 2 * DIM + lf);
        fx4 tp0 = *(const fx4*)(rb0 + 3 * DIM + lf);
        fx4 h1  = *(const fx4*)(rb1 + 0 * DIM + lf);
        fx4 hp1 = *(const fx4*)(rb1 + 1 * DIM + lf);
        fx4 t1  = *(const fx4*)(rb1 + 2 * DIM + lf);
        fx4 tp1 = *(const fx4*)(rb1 + 3 * DIM + lf);

        float a0 = dot4(h0, hp0), b0 = dot4(t0, tp0);
        float a1 = dot4(h1, hp1), b1 = dot4(t1, tp1);
#pragma unroll
        for (int m = 32; m > 0; m >>= 1) {
            a0 += __shfl_xor(a0, m, 64);
            b0 += __shfl_xor(b0, m, 64);
            a1 += __shfl_xor(a1, m, 64);
            b1 += __shfl_xor(b1, m, 64);
        }
        const float ab0 = a0 - b0, ab1 = a1 - b1;

        fx4 d0 = rpv[p2][0] * ab0 + h0 + rv[p2][0] - t0 + EPSV;
        fx4 d1 = rpv[p2][1] * ab1 + h1 + rv[p2][1] - t1 + EPSV;
        float ss0 = dot4(d0, d0), ss1 = dot4(d1, d1);
#pragma unroll
        for (int m = 32; m > 0; m >>= 1) {
            ss0 += __shfl_xor(ss0, m, 64);
            ss1 += __shfl_xor(ss1, m, 64);
        }
        const float v = sqrtf(ss0) - sqrtf(ss1) + MARGIN;
        accf += v > 0.0f ? v : 0.0f;
    }

    if (lane == 0) wsum[w] = accf;
    __syncthreads();
    if (tid == 0) {
        const float bsum = (wsum[0] + wsum[1]) + (wsum[2] + wsum[3]);
        // Fixed-point accumulate: bitwise-deterministic regardless of block order.
        const unsigned long long fx = (unsigned long long)((double)bsum * FXSCALE);
        atomicAdd(acc, fx);
        __threadfence();  // acc-add visible before the completion tick
        const unsigned int ticket = atomicAdd(done, 1u);
        if (ticket == NBLOCKS - 1) {
            const unsigned long long total = atomicAdd(acc, 0ull);  // atomic read
            out[0] = (float)((double)total / FXSCALE / (double)BATCH);
        }
    }
}

extern "C" void kernel_launch(void* const* d_in, const int* in_sizes, int n_in,
                              void* d_out, int out_size, void* d_ws, size_t ws_size,
                              hipStream_t stream) {
    const int*   pos_x = (const int*)d_in[0];
    const int*   neg_x = (const int*)d_in[1];
    const float* ent   = (const float*)d_in[2];
    const float* entm  = (const float*)d_in[3];
    const float* rel   = (const float*)d_in[4];
    const float* relm  = (const float*)d_in[5];

    unsigned long long* acc  = (unsigned long long*)d_ws;            // 8 B
    unsigned int*       done = (unsigned int*)((char*)d_ws + 8);     // 4 B
    float*              out  = (float*)d_out;

    // Zero the accumulator + counter each call (graph-capturable async memset).
    hipMemsetAsync(d_ws, 0, 16, stream);

    transd_loss_kernel<<<NBLOCKS, 256, 0, stream>>>(pos_x, neg_x, ent, entm, rel, relm,
                                                    acc, done, out);
}

// Round 7
// 33.989 us; speedup vs baseline: 2.7384x; 2.7384x over previous
//
#include <hip/hip_runtime.h>
#include <stdint.h>

#define DIM 256
#define BATCH 16384
#define MARGIN 1.0f
#define EPSV 1e-6f

#define WPB 4                         // waves per block
#define PPW 8                         // pairs per wave (pipelined loop)
#define MAIN_BLOCKS (BATCH / (WPB * PPW))  // 512 blocks = 2/CU, all resident
#define STAGE_FLOATS (8 * DIM)        // 8 rows (pos h,hp,t,tp + neg h,hp,t,tp) = 8KB
#define WAVE_LDS (2 * STAGE_FLOATS)   // per-wave double buffer = 16KB

typedef float fx4 __attribute__((ext_vector_type(4)));

__device__ __forceinline__ float dot4(fx4 a, fx4 b) {
    return a.x * b.x + a.y * b.y + a.z * b.z + a.w * b.w;
}

// Async global->LDS, 16B/lane; LDS dest = wave-uniform base + lane*16 (HW rule).
__device__ __forceinline__ void gload_lds16(const void* g, void* l) {
    __builtin_amdgcn_global_load_lds(
        (const __attribute__((address_space(1))) uint32_t*)g,
        (__attribute__((address_space(3))) uint32_t*)l, 16, 0, 0);
}

// Counted vmem wait (T4): literal N keeps N newest ops in flight.
#define WAITV(n) asm volatile("s_waitcnt vmcnt(" #n ")" ::: "memory")

// Per-wave barrier-free pipeline over 8 pairs. vmem ops per region:
//   LOAD_IDX = 6 (dword), ISSUE_STAGE = 8 DMA + 4 rel vec = 12.
// Issue order per iter j: LOAD_IDX(j+2) [6] -> ISSUE_STAGE(j+1) [12]
// (auto-wait for idx(j+1) regs hits the OLDEST ops -> vmcnt(18), pipe intact)
// -> manual WAITV(18) -> stage j retired -> compute pair j.
__global__ __launch_bounds__(256, 2) void transd_loss_kernel(
    const int* __restrict__ pos_x, const int* __restrict__ neg_x,
    const float* __restrict__ ent, const float* __restrict__ entm,
    const float* __restrict__ rel, const float* __restrict__ relm,
    float* __restrict__ partial) {
    __shared__ float rows[WPB * WAVE_LDS];  // 64 KB
    __shared__ float wsum[WPB];

    const int tid  = threadIdx.x;
    const int w    = tid >> 6;
    const int lane = tid & 63;
    const int lf   = lane * 4;                       // float offset, 16B/lane
    const int p0   = (blockIdx.x * WPB + w) * PPW;   // first pair of this wave
    float* wbuf = &rows[w * WAVE_LDS];

    int ph[2], pr[2], pt[2], nh[2], nr[2], nt[2];    // idx double-buffer
    fx4 rv[2][2], rpv[2][2];                         // rel rows [buf][side]

#define LOAD_IDX(b, j) do {                                              \
        const int p_ = p0 + (j);                                         \
        ph[b] = pos_x[p_ * 3 + 0];                                       \
        pr[b] = pos_x[p_ * 3 + 1];                                       \
        pt[b] = pos_x[p_ * 3 + 2];                                       \
        nh[b] = neg_x[p_ * 3 + 0];                                       \
        nr[b] = neg_x[p_ * 3 + 1];                                       \
        nt[b] = neg_x[p_ * 3 + 2];                                       \
    } while (0)

#define ISSUE_STAGE(b) do {                                              \
        float* sb_ = wbuf + (b) * STAGE_FLOATS;                          \
        const size_t hop = (size_t)ph[b] * DIM + lf;                     \
        const size_t top = (size_t)pt[b] * DIM + lf;                     \
        const size_t hon = (size_t)nh[b] * DIM + lf;                     \
        const size_t ton = (size_t)nt[b] * DIM + lf;                     \
        gload_lds16(ent  + hop, sb_ + 0 * DIM);                          \
        gload_lds16(entm + hop, sb_ + 1 * DIM);                          \
        gload_lds16(ent  + top, sb_ + 2 * DIM);                          \
        gload_lds16(entm + top, sb_ + 3 * DIM);                          \
        gload_lds16(ent  + hon, sb_ + 4 * DIM);                          \
        gload_lds16(entm + hon, sb_ + 5 * DIM);                          \
        gload_lds16(ent  + ton, sb_ + 6 * DIM);                          \
        gload_lds16(entm + ton, sb_ + 7 * DIM);                          \
        const size_t rop = (size_t)pr[b] * DIM + lf;                     \
        const size_t ron = (size_t)nr[b] * DIM + lf;                     \
        rv[b][0]  = *(const fx4*)(rel  + rop);                           \
        rpv[b][0] = *(const fx4*)(relm + rop);                           \
        rv[b][1]  = *(const fx4*)(rel  + ron);                           \
        rpv[b][1] = *(const fx4*)(relm + ron);                           \
    } while (0)

    // Prolog: idx0, idx1, stage0.
    LOAD_IDX(0, 0);
    LOAD_IDX(1, 1);
    ISSUE_STAGE(0);   // auto-wait vmcnt(6) for idx0; idx1 stays in flight

    float acc = 0.0f;
#pragma unroll
    for (int j = 0; j < PPW; ++j) {
        const int cb = j & 1;        // compute buffer
        const int nb = (j + 1) & 1;  // next-stage buffer
        if (j + 2 < PPW) LOAD_IDX(cb, j + 2);   // 6 ops (overwrites consumed idx)
        if (j + 1 < PPW) ISSUE_STAGE(nb);       // 12 ops (auto-wait hits oldest idx)

        // Counted wait: retire stage j, keep {idx(j+2), stage(j+1)} in flight.
        if (j <= PPW - 3)      { WAITV(18); }
        else if (j == PPW - 2) { WAITV(12); }
        else                   { WAITV(0);  }
        __builtin_amdgcn_sched_barrier(0);

        const float* sb = wbuf + cb * STAGE_FLOATS;
        fx4 h0  = *(const fx4*)(sb + 0 * DIM + lf);
        fx4 hp0 = *(const fx4*)(sb + 1 * DIM + lf);
        fx4 t0  = *(const fx4*)(sb + 2 * DIM + lf);
        fx4 tp0 = *(const fx4*)(sb + 3 * DIM + lf);
        fx4 h1  = *(const fx4*)(sb + 4 * DIM + lf);
        fx4 hp1 = *(const fx4*)(sb + 5 * DIM + lf);
        fx4 t1  = *(const fx4*)(sb + 6 * DIM + lf);
        fx4 tp1 = *(const fx4*)(sb + 7 * DIM + lf);

        float a0 = dot4(h0, hp0), b0 = dot4(t0, tp0);
        float a1 = dot4(h1, hp1), b1 = dot4(t1, tp1);
#pragma unroll
        for (int m = 32; m > 0; m >>= 1) {
            a0 += __shfl_xor(a0, m, 64);
            b0 += __shfl_xor(b0, m, 64);
            a1 += __shfl_xor(a1, m, 64);
            b1 += __shfl_xor(b1, m, 64);
        }
        const float ab0 = a0 - b0, ab1 = a1 - b1;

        fx4 d0 = rpv[cb][0] * ab0 + h0 + rv[cb][0] - t0 + EPSV;
        fx4 d1 = rpv[cb][1] * ab1 + h1 + rv[cb][1] - t1 + EPSV;
        float ss0 = dot4(d0, d0), ss1 = dot4(d1, d1);
#pragma unroll
        for (int m = 32; m > 0; m >>= 1) {
            ss0 += __shfl_xor(ss0, m, 64);
            ss1 += __shfl_xor(ss1, m, 64);
        }
        const float v = sqrtf(ss0) - sqrtf(ss1) + MARGIN;
        acc += v > 0.0f ? v : 0.0f;
    }
#undef LOAD_IDX
#undef ISSUE_STAGE

    if (lane == 0) wsum[w] = acc;
    __syncthreads();
    if (tid == 0)
        partial[blockIdx.x] = (wsum[0] + wsum[1]) + (wsum[2] + wsum[3]);
}

// Deterministic single-block reduction of MAIN_BLOCKS floats -> out[0] = sum/BATCH.
__global__ __launch_bounds__(256) void reduce_kernel(const float* __restrict__ partial,
                                                     float* __restrict__ out) {
    const int lane = threadIdx.x & 63;
    float s = 0.0f;
    for (int i = threadIdx.x; i < MAIN_BLOCKS; i += 256) s += partial[i];
#pragma unroll
    for (int m = 32; m > 0; m >>= 1) s += __shfl_xor(s, m, 64);
    __shared__ float smem[4];
    if (lane == 0) smem[threadIdx.x >> 6] = s;
    __syncthreads();
    if (threadIdx.x == 0)
        out[0] = ((smem[0] + smem[1]) + (smem[2] + smem[3])) / (float)BATCH;
}

extern "C" void kernel_launch(void* const* d_in, const int* in_sizes, int n_in,
                              void* d_out, int out_size, void* d_ws, size_t ws_size,
                              hipStream_t stream) {
    const int*   pos_x = (const int*)d_in[0];
    const int*   neg_x = (const int*)d_in[1];
    const float* ent   = (const float*)d_in[2];
    const float* entm  = (const float*)d_in[3];
    const float* rel   = (const float*)d_in[4];
    const float* relm  = (const float*)d_in[5];

    float* partial = (float*)d_ws;  // MAIN_BLOCKS floats = 2 KB
    float* out     = (float*)d_out;

    transd_loss_kernel<<<MAIN_BLOCKS, 256, 0, stream>>>(pos_x, neg_x, ent, entm, rel, relm, partial);
    reduce_kernel<<<1, 256, 0, stream>>>(partial, out);
}